// Round 14
// baseline (130.649 us; speedup 1.0000x reference)
//
#include <hip/hip_runtime.h>
#include <math.h>

// Problem constants
#define R_ 5
#define NN 68        // N_NODES == LATENT
#define KK 32        // neighbors per node
#define NL 3         // GCN layers
#define LAT 68
#define NSL 17               // nodes per wave slice (4 waves x 17 = 68)
#define ROWQ (NN / 4)        // 17 float4 per node row
#define NF4 ((NN * NN) / 4)  // 1156 float4 per output row
#define BBK2 16              // batches per K2 block
#define LSTR 344             // LDS row stride (floats) for K2, 16B-aligned
#define NPREP (R_ * NL)      // 15 densify blocks inside prep_k

typedef float f32x4 __attribute__((ext_vector_type(4)));  // nontemporal-legal

// ---------------- P: merged prep (densify + z-transpose) ----------------
__global__ __launch_bounds__(256) void prep_k(
    const float* __restrict__ z, const int* __restrict__ adj,
    const float* __restrict__ gw, float* __restrict__ wd,
    float* __restrict__ zT, int B) {
  const int t = threadIdx.x;
  if (blockIdx.x < NPREP) {
    const int rl = blockIdx.x;  // r*NL + l
    __shared__ float col[NN][NN + 4];
    for (int i = t; i < NN * (NN + 4); i += 256) (&col[0][0])[i] = 0.0f;
    __syncthreads();
    if (t < NN) {
      const int n = t;  // thread owns column n -> no races
      const int* ar = adj + n * KK;
      const float* wr = gw + ((size_t)rl * NN + n) * KK;
      for (int k = 0; k < KK; ++k) col[ar[k]][n] += wr[k];
    }
    __syncthreads();
    float* wout = wd + (size_t)rl * NN * NN;  // [m][n], n contiguous
    for (int i = t; i < NN * NN; i += 256) {
      const int m = i / NN, n = i - m * NN;
      wout[i] = col[m][n];
    }
  } else {
    const int b0 = (blockIdx.x - NPREP) * 64;
    __shared__ float zls[64][LAT + 1];  // +1: stride 69, conflict-free
    for (int idx = t; idx < 64 * ROWQ; idx += 256) {
      const int row = idx / ROWQ, q = idx - row * ROWQ;
      const float4 v =
          *reinterpret_cast<const float4*>(z + (size_t)(b0 + row) * LAT + 4 * q);
      zls[row][4 * q + 0] = v.x;
      zls[row][4 * q + 1] = v.y;
      zls[row][4 * q + 2] = v.z;
      zls[row][4 * q + 3] = v.w;
    }
    __syncthreads();
    for (int idx = t; idx < LAT * 64; idx += 256) {
      const int l = idx >> 6, bb = idx & 63;
      zT[(size_t)l * B + b0 + bb] = zls[bb][l];
    }
  }
}

// ---------------- K1: GEMM-chain (v12 verbatim — chunked m, s_load path) ---
__global__ __launch_bounds__(256) void chain_k(
    const float* __restrict__ zT, const float* __restrict__ fc_w,
    const float* __restrict__ fc_b, const float* __restrict__ wd,
    const float* __restrict__ gb, float* __restrict__ X, int B, int nb) {
  const int t = threadIdx.x;
  const int lane = t & 63;
  const int w = __builtin_amdgcn_readfirstlane(t >> 6);
  const int n0 = w * NSL;  // first node of this wave's slice (wave-uniform)
  const int r = blockIdx.x / nb;
  const int b0 = (blockIdx.x - r * nb) * 64;

  __shared__ float xs[NN][64];  // 17.4 KB; z, then x, per stage

  for (int idx = t; idx < NN * 64; idx += 256) {
    const int m = idx >> 6;
    xs[m][idx & 63] = zT[(size_t)m * B + b0 + (idx & 63)];
  }
  __syncthreads();

  float acc[NSL];

#pragma unroll 1
  for (int stage = 0; stage < 1 + NL; ++stage) {
    const float* wb = (stage == 0) ? fc_w + (size_t)r * LAT * NN
                                   : wd + (size_t)(r * NL + stage - 1) * NN * NN;
    const float* bias = (stage == 0) ? fc_b + r * NN
                                     : gb + (size_t)(r * NL + stage - 1) * NN;
#pragma unroll
    for (int j = 0; j < NSL; ++j) acc[j] = bias[n0 + j];  // uniform -> s_load

#pragma unroll 1
    for (int mb = 0; mb < 4; ++mb) {  // 4 chunks of 17 rows
      float xmv[NSL];                 // statically indexed -> stays in VGPRs
#pragma unroll
      for (int k = 0; k < NSL; ++k) xmv[k] = xs[mb * NSL + k][lane];
      const float* wrb = wb + (size_t)(mb * NSL) * NN + n0;
#pragma unroll
      for (int k = 0; k < NSL; ++k) {
        const float* wr = wrb + (size_t)k * NN;  // wave-uniform -> s_load
#pragma unroll
        for (int j = 0; j < NSL; ++j) acc[j] = fmaf(xmv[k], wr[j], acc[j]);
      }
    }
    if (stage > 0) {
#pragma unroll
      for (int j = 0; j < NSL; ++j)
        acc[j] = 1.0f / (1.0f + __expf(-acc[j]));
    }
    if (stage < NL) {
      __syncthreads();  // everyone done READING xs for this stage
#pragma unroll
      for (int j = 0; j < NSL; ++j) xs[n0 + j][lane] = acc[j];
      __syncthreads();
    }
  }

  // ---- final X -> ws, layout [r*68+n][b]: coalesced 256B rows ----
  float* Xb = X + ((size_t)r * NN + n0) * B + b0 + lane;
#pragma unroll
  for (int j = 0; j < NSL; ++j) Xb[(size_t)j * B] = acc[j];
}

// ---------------- K2: outer product, flat + NONTEMPORAL full-line stores ---
// v6-flat structure (measured-best): consecutive lanes write consecutive f4
// -> each wave-instr is a 1024B contiguous, 64B-aligned run (block base
// 295936B = 64-multiple) -> full lines only. nt bypasses L2 write-allocate/
// eviction (the suspected 4.3 TB/s cap); v8's nt failure was its misaligned
// 272B partial-line segments, which don't exist here.
__global__ __launch_bounds__(256) void outer_k(const float* __restrict__ X,
                                               float* __restrict__ out, int B) {
  const int t = threadIdx.x;
  const int b0 = blockIdx.x * BBK2;
  __shared__ float xls[BBK2 * LSTR];

  // stage X[rn][b0..b0+15] -> xls[bb][rn]; reads are exact 64B lines
  for (int idx = t; idx < R_ * NN * BBK2; idx += 256) {
    const int rn = idx >> 4, bb = idx & (BBK2 - 1);
    xls[bb * LSTR + rn] = X[(size_t)rn * B + b0 + bb];
  }
  __syncthreads();

  f32x4* ob = reinterpret_cast<f32x4*>(out) + (size_t)b0 * NF4;
  const int total = BBK2 * NF4;  // 18496
  for (int fg = t; fg < total; fg += 256) {
    const int bb = fg / NF4;
    const int f = fg - bb * NF4;
    const int i = f / ROWQ;
    const int q = f - i * ROWQ;
    const float* xb = &xls[bb * LSTR];
    float4 a = make_float4(0.f, 0.f, 0.f, 0.f);
#pragma unroll
    for (int r = 0; r < R_; ++r) {
      const float xi = xb[r * NN + i];
      const float4 xj = *reinterpret_cast<const float4*>(xb + r * NN + 4 * q);
      a.x = fmaf(xi, xj.x, a.x);
      a.y = fmaf(xi, xj.y, a.y);
      a.z = fmaf(xi, xj.z, a.z);
      a.w = fmaf(xi, xj.w, a.w);
    }
    f32x4 av = {a.x, a.y, a.z, a.w};
    __builtin_nontemporal_store(av, &ob[fg]);  // full-line streaming store
  }
}

extern "C" void kernel_launch(void* const* d_in, const int* in_sizes, int n_in,
                              void* d_out, int out_size, void* d_ws, size_t ws_size,
                              hipStream_t stream) {
  const float* z    = (const float*)d_in[0];  // (16384, 68)
  const int*   adj  = (const int*)  d_in[1];  // (68, 32)
  const float* fc_w = (const float*)d_in[2];  // (5, 68, 68)
  const float* fc_b = (const float*)d_in[3];  // (5, 68)
  const float* gw   = (const float*)d_in[4];  // (5, 3, 68, 32)
  const float* gb   = (const float*)d_in[5];  // (5, 3, 68)
  float* out = (float*)d_out;                 // (16384, 4624)

  const int B = in_sizes[0] / LAT;            // 16384
  // ws layout (f32): wd[15*68*68] | zT[68*B] | X[340*B]  (~27.1 MB total)
  float* wd = (float*)d_ws;
  float* zT = wd + R_ * NL * NN * NN;
  float* X  = zT + (size_t)LAT * B;

  const int nb = B / 64;                      // 256 batch-groups (chain)

  prep_k<<<NPREP + B / 64, 256, 0, stream>>>(z, adj, gw, wd, zT, B);
  chain_k<<<R_ * nb, 256, 0, stream>>>(zT, fc_w, fc_b, wd, gb, X, B, nb);
  outer_k<<<B / BBK2, 256, 0, stream>>>(X, out, B);
}

// Round 15
// 129.403 us; speedup vs baseline: 1.0096x; 1.0096x over previous
//
#include <hip/hip_runtime.h>
#include <math.h>

// Problem constants
#define R_ 5
#define NN 68        // N_NODES == LATENT
#define KK 32        // neighbors per node
#define NL 3         // GCN layers
#define LAT 68
#define NSL 17               // nodes per wave slice (4 waves x 17 = 68)
#define SLP 20               // padded slice stride (floats): 80B, 16B-aligned
#define MST (4 * SLP)        // per-row stride in wpack (80 floats)
#define ROWQ (NN / 4)        // 17 float4 per node row
#define NF4 ((NN * NN) / 4)  // 1156 float4 per output row
#define BBK2 16              // batches per K2 block
#define LSTR 344             // LDS row stride (floats) for K2, 16B-aligned
#define WPACK_FLOATS (R_ * 4 * NN * MST)   // 108800
#define BPACK_FLOATS (R_ * 4 * 4 * SLP)    // 1600

typedef float f32x4 __attribute__((ext_vector_type(4)));

// ---------------- P: merged prep (densify+pack, fc/bias pack, z-transpose) --
// blocks [0,15): densify gw -> wpack stages 1..3 (aligned 20-float slices)
// blocks [15,20): repack fc_w -> wpack stage 0; pack all biases -> bpack
// blocks [20, 20+B/64): zT[l][b] transpose tiles
__global__ __launch_bounds__(256) void prep_k(
    const float* __restrict__ z, const int* __restrict__ adj,
    const float* __restrict__ fc_w, const float* __restrict__ fc_b,
    const float* __restrict__ gw, const float* __restrict__ gb,
    float* __restrict__ wpack, float* __restrict__ bpack,
    float* __restrict__ zT, int B) {
  const int t = threadIdx.x;
  if (blockIdx.x < R_ * NL) {
    const int rl = blockIdx.x;  // r*NL + l
    const int r = rl / NL, l = rl - r * NL;
    const int stage = 1 + l;
    __shared__ float col[NN][NN + 4];
    for (int i = t; i < NN * (NN + 4); i += 256) (&col[0][0])[i] = 0.0f;
    __syncthreads();
    if (t < NN) {
      const int n = t;  // thread owns column n -> no races
      const int* ar = adj + n * KK;
      const float* wr = gw + ((size_t)rl * NN + n) * KK;
      for (int k = 0; k < KK; ++k) col[ar[k]][n] += wr[k];
    }
    __syncthreads();
    for (int i = t; i < NN * NN; i += 256) {
      const int m = i / NN, n = i - m * NN;
      const int w = n / NSL, j = n - w * NSL;
      wpack[(size_t)((r * 4 + stage) * NN + m) * MST + w * SLP + j] = col[m][n];
    }
  } else if (blockIdx.x < R_ * NL + R_) {
    const int r = blockIdx.x - R_ * NL;
    for (int i = t; i < NN * NN; i += 256) {
      const int m = i / NN, n = i - m * NN;
      const int w = n / NSL, j = n - w * NSL;
      wpack[(size_t)((r * 4 + 0) * NN + m) * MST + w * SLP + j] =
          fc_w[((size_t)r * NN + m) * NN + n];
    }
    for (int i = t; i < 4 * NN; i += 256) {  // 272 bias entries (stages 0..3)
      const int st = i / NN, n = i - st * NN;
      const int w = n / NSL, j = n - w * NSL;
      const float v = (st == 0) ? fc_b[r * NN + n]
                                : gb[((size_t)r * NL + st - 1) * NN + n];
      bpack[((r * 4 + st) * 4 + w) * SLP + j] = v;
    }
  } else {
    const int b0 = (blockIdx.x - (R_ * NL + R_)) * 64;
    __shared__ float zls[64][LAT + 1];  // +1: stride 69, conflict-free
    for (int idx = t; idx < 64 * ROWQ; idx += 256) {
      const int row = idx / ROWQ, q = idx - row * ROWQ;
      const float4 v =
          *reinterpret_cast<const float4*>(z + (size_t)(b0 + row) * LAT + 4 * q);
      zls[row][4 * q + 0] = v.x;
      zls[row][4 * q + 1] = v.y;
      zls[row][4 * q + 2] = v.z;
      zls[row][4 * q + 3] = v.w;
    }
    __syncthreads();
    for (int idx = t; idx < LAT * 64; idx += 256) {
      const int l = idx >> 6, bb = idx & 63;
      zT[(size_t)l * B + b0 + bb] = zls[bb][l];
    }
  }
}

// ---------------- K1: GEMM-chain — chunked m + ALIGNED wide s_loads --------
// v12 structure; weight rows now read as 4x s_load_dwordx4 + 1x s_load_dword
// (slice base 16B-aligned in wpack) instead of 17x s_load_dword: SMEM issue
// count per CU drops 92k -> 27k cycles, below the 19us VALU floor.
__global__ __launch_bounds__(256) void chain_k(
    const float* __restrict__ zT, const float* __restrict__ wpack,
    const float* __restrict__ bpack, float* __restrict__ X, int B, int nb) {
  const int t = threadIdx.x;
  const int lane = t & 63;
  const int w = __builtin_amdgcn_readfirstlane(t >> 6);
  const int n0 = w * NSL;  // first node of this wave's slice (wave-uniform)
  const int r = blockIdx.x / nb;
  const int b0 = (blockIdx.x - r * nb) * 64;

  __shared__ float xs[NN][64];  // 17.4 KB; z, then x, per stage

  for (int idx = t; idx < NN * 64; idx += 256) {
    const int m = idx >> 6;
    xs[m][idx & 63] = zT[(size_t)m * B + b0 + (idx & 63)];
  }
  __syncthreads();

  float acc[NSL];

#pragma unroll 1
  for (int stage = 0; stage < 1 + NL; ++stage) {
    const float* wb =
        wpack + (size_t)((r * 4 + stage) * NN) * MST + w * SLP;  // uniform
    const float* bp = bpack + ((r * 4 + stage) * 4 + w) * SLP;   // uniform
    {
      const f32x4* bp4 = reinterpret_cast<const f32x4*>(bp);
      f32x4 b0v = bp4[0], b1v = bp4[1], b2v = bp4[2], b3v = bp4[3];
      const float b16 = bp[16];
      f32x4 bq[4] = {b0v, b1v, b2v, b3v};
#pragma unroll
      for (int j = 0; j < 16; ++j) acc[j] = bq[j >> 2][j & 3];
      acc[16] = b16;
    }

#pragma unroll 1
    for (int mb = 0; mb < 4; ++mb) {  // 4 chunks of 17 rows
      float xmv[NSL];                 // statically indexed -> stays in VGPRs
#pragma unroll
      for (int k = 0; k < NSL; ++k) xmv[k] = xs[mb * NSL + k][lane];
#pragma unroll
      for (int k = 0; k < NSL; ++k) {
        const float* wr = wb + (size_t)(mb * NSL + k) * MST;  // 16B-aligned
        const f32x4* wr4 = reinterpret_cast<const f32x4*>(wr);
        f32x4 wq[4];
#pragma unroll
        for (int q = 0; q < 4; ++q) wq[q] = wr4[q];  // s_load_dwordx4 x4
        const float w16 = wr[16];                    // s_load_dword
#pragma unroll
        for (int j = 0; j < 16; ++j)
          acc[j] = fmaf(xmv[k], wq[j >> 2][j & 3], acc[j]);
        acc[16] = fmaf(xmv[k], w16, acc[16]);
      }
    }
    if (stage > 0) {
#pragma unroll
      for (int j = 0; j < NSL; ++j)
        acc[j] = 1.0f / (1.0f + __expf(-acc[j]));
    }
    if (stage < NL) {
      __syncthreads();  // everyone done READING xs for this stage
#pragma unroll
      for (int j = 0; j < NSL; ++j) xs[n0 + j][lane] = acc[j];
      __syncthreads();
    }
  }

  // ---- final X -> ws, layout [r*68+n][b]: coalesced 256B rows ----
  float* Xb = X + ((size_t)r * NN + n0) * B + b0 + lane;
#pragma unroll
  for (int j = 0; j < NSL; ++j) Xb[(size_t)j * B] = acc[j];
}

// ---------------- K2: outer product + store (v12 verbatim, measured-best) --
__global__ __launch_bounds__(256) void outer_k(const float* __restrict__ X,
                                               float* __restrict__ out, int B) {
  const int t = threadIdx.x;
  const int b0 = blockIdx.x * BBK2;
  __shared__ float xls[BBK2 * LSTR];

  // stage X[rn][b0..b0+15] -> xls[bb][rn]; reads are exact 64B lines
  for (int idx = t; idx < R_ * NN * BBK2; idx += 256) {
    const int rn = idx >> 4, bb = idx & (BBK2 - 1);
    xls[bb * LSTR + rn] = X[(size_t)rn * B + b0 + bb];
  }
  __syncthreads();

  float4* ob = reinterpret_cast<float4*>(out) + (size_t)b0 * NF4;
  const int total = BBK2 * NF4;  // 18496
  for (int fg = t; fg < total; fg += 256) {
    const int bb = fg / NF4;
    const int f = fg - bb * NF4;
    const int i = f / ROWQ;
    const int q = f - i * ROWQ;
    const float* xb = &xls[bb * LSTR];
    float4 a = make_float4(0.f, 0.f, 0.f, 0.f);
#pragma unroll
    for (int r = 0; r < R_; ++r) {
      const float xi = xb[r * NN + i];
      const float4 xj = *reinterpret_cast<const float4*>(xb + r * NN + 4 * q);
      a.x = fmaf(xi, xj.x, a.x);
      a.y = fmaf(xi, xj.y, a.y);
      a.z = fmaf(xi, xj.z, a.z);
      a.w = fmaf(xi, xj.w, a.w);
    }
    ob[fg] = a;  // lanes consecutive -> perfectly coalesced
  }
}

extern "C" void kernel_launch(void* const* d_in, const int* in_sizes, int n_in,
                              void* d_out, int out_size, void* d_ws, size_t ws_size,
                              hipStream_t stream) {
  const float* z    = (const float*)d_in[0];  // (16384, 68)
  const int*   adj  = (const int*)  d_in[1];  // (68, 32)
  const float* fc_w = (const float*)d_in[2];  // (5, 68, 68)
  const float* fc_b = (const float*)d_in[3];  // (5, 68)
  const float* gw   = (const float*)d_in[4];  // (5, 3, 68, 32)
  const float* gb   = (const float*)d_in[5];  // (5, 3, 68)
  float* out = (float*)d_out;                 // (16384, 4624)

  const int B = in_sizes[0] / LAT;            // 16384
  // ws layout (f32): wpack[108800] | bpack[1600] | zT[68*B] | X[340*B]
  // total ~27.2 MB
  float* wpack = (float*)d_ws;
  float* bpack = wpack + WPACK_FLOATS;
  float* zT = bpack + BPACK_FLOATS;
  float* X  = zT + (size_t)LAT * B;

  const int nb = B / 64;                      // 256 batch-groups (chain)

  prep_k<<<R_ * NL + R_ + B / 64, 256, 0, stream>>>(z, adj, fc_w, fc_b, gw, gb,
                                                    wpack, bpack, zT, B);
  chain_k<<<R_ * nb, 256, 0, stream>>>(zT, wpack, bpack, X, B, nb);
  outer_k<<<B / BBK2, 256, 0, stream>>>(X, out, B);
}

// Round 16
// 123.999 us; speedup vs baseline: 1.0536x; 1.0436x over previous
//
#include <hip/hip_runtime.h>
#include <math.h>

// Problem constants
#define R_ 5
#define NN 68        // N_NODES == LATENT
#define KK 32        // neighbors per node
#define NL 3         // GCN layers
#define LAT 68
#define NSL 17               // nodes per wave slice (4 waves x 17 = 68)
#define ROWQ (NN / 4)        // 17 float4 per node row
#define NF4 ((NN * NN) / 4)  // 1156 float4 per output row
#define BBK2 16              // batches per K2 block
#define LSTR 344             // LDS row stride (floats) for K2, 16B-aligned
#define NPREP (R_ * NL)      // 15 densify blocks inside prep_k

// ---------------- P: merged prep (densify + z-transpose) ----------------
__global__ __launch_bounds__(256) void prep_k(
    const float* __restrict__ z, const int* __restrict__ adj,
    const float* __restrict__ gw, float* __restrict__ wd,
    float* __restrict__ zT, int B) {
  const int t = threadIdx.x;
  if (blockIdx.x < NPREP) {
    const int rl = blockIdx.x;  // r*NL + l
    __shared__ float col[NN][NN + 4];
    for (int i = t; i < NN * (NN + 4); i += 256) (&col[0][0])[i] = 0.0f;
    __syncthreads();
    if (t < NN) {
      const int n = t;  // thread owns column n -> no races
      const int* ar = adj + n * KK;
      const float* wr = gw + ((size_t)rl * NN + n) * KK;
      for (int k = 0; k < KK; ++k) col[ar[k]][n] += wr[k];
    }
    __syncthreads();
    float* wout = wd + (size_t)rl * NN * NN;  // [m][n], n contiguous
    for (int i = t; i < NN * NN; i += 256) {
      const int m = i / NN, n = i - m * NN;
      wout[i] = col[m][n];
    }
  } else {
    const int b0 = (blockIdx.x - NPREP) * 64;
    __shared__ float zls[64][LAT + 1];  // +1: stride 69, conflict-free
    for (int idx = t; idx < 64 * ROWQ; idx += 256) {
      const int row = idx / ROWQ, q = idx - row * ROWQ;
      const float4 v =
          *reinterpret_cast<const float4*>(z + (size_t)(b0 + row) * LAT + 4 * q);
      zls[row][4 * q + 0] = v.x;
      zls[row][4 * q + 1] = v.y;
      zls[row][4 * q + 2] = v.z;
      zls[row][4 * q + 3] = v.w;
    }
    __syncthreads();
    for (int idx = t; idx < LAT * 64; idx += 256) {
      const int l = idx >> 6, bb = idx & 63;
      zT[(size_t)l * B + b0 + bb] = zls[bb][l];
    }
  }
}

// ---------------- K1: GEMM-chain (v12 verbatim — chunked m, s_load path) ---
__global__ __launch_bounds__(256) void chain_k(
    const float* __restrict__ zT, const float* __restrict__ fc_w,
    const float* __restrict__ fc_b, const float* __restrict__ wd,
    const float* __restrict__ gb, float* __restrict__ X, int B, int nb) {
  const int t = threadIdx.x;
  const int lane = t & 63;
  const int w = __builtin_amdgcn_readfirstlane(t >> 6);
  const int n0 = w * NSL;  // first node of this wave's slice (wave-uniform)
  const int r = blockIdx.x / nb;
  const int b0 = (blockIdx.x - r * nb) * 64;

  __shared__ float xs[NN][64];  // 17.4 KB; z, then x, per stage

  for (int idx = t; idx < NN * 64; idx += 256) {
    const int m = idx >> 6;
    xs[m][idx & 63] = zT[(size_t)m * B + b0 + (idx & 63)];
  }
  __syncthreads();

  float acc[NSL];

#pragma unroll 1
  for (int stage = 0; stage < 1 + NL; ++stage) {
    const float* wb = (stage == 0) ? fc_w + (size_t)r * LAT * NN
                                   : wd + (size_t)(r * NL + stage - 1) * NN * NN;
    const float* bias = (stage == 0) ? fc_b + r * NN
                                     : gb + (size_t)(r * NL + stage - 1) * NN;
#pragma unroll
    for (int j = 0; j < NSL; ++j) acc[j] = bias[n0 + j];  // uniform -> s_load

#pragma unroll 1
    for (int mb = 0; mb < 4; ++mb) {  // 4 chunks of 17 rows
      float xmv[NSL];                 // statically indexed -> stays in VGPRs
#pragma unroll
      for (int k = 0; k < NSL; ++k) xmv[k] = xs[mb * NSL + k][lane];
      const float* wrb = wb + (size_t)(mb * NSL) * NN + n0;
#pragma unroll
      for (int k = 0; k < NSL; ++k) {
        const float* wr = wrb + (size_t)k * NN;  // wave-uniform -> s_load
#pragma unroll
        for (int j = 0; j < NSL; ++j) acc[j] = fmaf(xmv[k], wr[j], acc[j]);
      }
    }
    if (stage > 0) {
#pragma unroll
      for (int j = 0; j < NSL; ++j)
        acc[j] = 1.0f / (1.0f + __expf(-acc[j]));
    }
    if (stage < NL) {
      __syncthreads();  // everyone done READING xs for this stage
#pragma unroll
      for (int j = 0; j < NSL; ++j) xs[n0 + j][lane] = acc[j];
      __syncthreads();
    }
  }

  // ---- final X -> ws, layout [r*68+n][b]: coalesced 256B rows ----
  float* Xb = X + ((size_t)r * NN + n0) * B + b0 + lane;
#pragma unroll
  for (int j = 0; j < NSL; ++j) Xb[(size_t)j * B] = acc[j];
}

// ---------------- K2: outer product, flat store, 4-DEEP STORE PIPELINE -----
// v12's flat structure, but each macro-iteration computes FOUR independent
// accumulator sets (av[0..3], distinct VGPRs) and then issues the 4 stores
// back-to-back: 4 KB in flight per wave instead of 1 KB. Rationale: all four
// prior outer variants (73-80us, LDS traffic differing 9x) shared exactly one
// property — 1 store in flight/wave (compiler inserts vmcnt(0) before the
// accumulator VGPRs are overwritten each iteration). 16 waves/CU x 1KB =
// 16KB/CU in flight ~= BW*latency -> the measured 4.3 TB/s cap.
__global__ __launch_bounds__(256) void outer_k(const float* __restrict__ X,
                                               float* __restrict__ out, int B) {
  const int t = threadIdx.x;
  const int b0 = blockIdx.x * BBK2;
  __shared__ float xls[BBK2 * LSTR];

  // stage X[rn][b0..b0+15] -> xls[bb][rn]; reads are exact 64B lines
  for (int idx = t; idx < R_ * NN * BBK2; idx += 256) {
    const int rn = idx >> 4, bb = idx & (BBK2 - 1);
    xls[bb * LSTR + rn] = X[(size_t)rn * B + b0 + bb];
  }
  __syncthreads();

  float4* ob = reinterpret_cast<float4*>(out) + (size_t)b0 * NF4;
  const int total = BBK2 * NF4;  // 18496 = 18*1024 + 64
#pragma unroll 1
  for (int base = t; base < total; base += 1024) {
    float4 av[4];  // 4 independent accumulator sets (statically indexed)
#pragma unroll
    for (int u = 0; u < 4; ++u) {
      const int fg = base + u * 256;
      if (fg < total) {
        const int bb = fg / NF4;
        const int f = fg - bb * NF4;
        const int i = f / ROWQ;
        const int q = f - i * ROWQ;
        const float* xb = &xls[bb * LSTR];
        float4 a = make_float4(0.f, 0.f, 0.f, 0.f);
#pragma unroll
        for (int r = 0; r < R_; ++r) {
          const float xi = xb[r * NN + i];
          const float4 xj =
              *reinterpret_cast<const float4*>(xb + r * NN + 4 * q);
          a.x = fmaf(xi, xj.x, a.x);
          a.y = fmaf(xi, xj.y, a.y);
          a.z = fmaf(xi, xj.z, a.z);
          a.w = fmaf(xi, xj.w, a.w);
        }
        av[u] = a;
      }
    }
    // issue the 4 stores back-to-back -> 4 outstanding per wave
#pragma unroll
    for (int u = 0; u < 4; ++u) {
      const int fg = base + u * 256;
      if (fg < total) ob[fg] = av[u];  // lanes consecutive -> 1KB coalesced
    }
  }
}

extern "C" void kernel_launch(void* const* d_in, const int* in_sizes, int n_in,
                              void* d_out, int out_size, void* d_ws, size_t ws_size,
                              hipStream_t stream) {
  const float* z    = (const float*)d_in[0];  // (16384, 68)
  const int*   adj  = (const int*)  d_in[1];  // (68, 32)
  const float* fc_w = (const float*)d_in[2];  // (5, 68, 68)
  const float* fc_b = (const float*)d_in[3];  // (5, 68)
  const float* gw   = (const float*)d_in[4];  // (5, 3, 68, 32)
  const float* gb   = (const float*)d_in[5];  // (5, 3, 68)
  float* out = (float*)d_out;                 // (16384, 4624)

  const int B = in_sizes[0] / LAT;            // 16384
  // ws layout (f32): wd[15*68*68] | zT[68*B] | X[340*B]  (~27.1 MB total)
  float* wd = (float*)d_ws;
  float* zT = wd + R_ * NL * NN * NN;
  float* X  = zT + (size_t)LAT * B;

  const int nb = B / 64;                      // 256 batch-groups (chain)

  prep_k<<<NPREP + B / 64, 256, 0, stream>>>(z, adj, gw, wd, zT, B);
  chain_k<<<R_ * nb, 256, 0, stream>>>(zT, fc_w, fc_b, wd, gb, X, B, nb);
  outer_k<<<B / BBK2, 256, 0, stream>>>(X, out, B);
}